// Round 7
// baseline (123.022 us; speedup 1.0000x reference)
//
#include <hip/hip_runtime.h>
#include <hip/hip_bf16.h>

#define BB 16
#define NQ 64
#define NK 512
#define HD 256   // H = QS = KS = VD = 256

typedef __attribute__((ext_vector_type(8))) short short8;
typedef __attribute__((ext_vector_type(4))) float f32x4;

__device__ __forceinline__ ushort bf16_rne(float v) {
    unsigned u = __float_as_uint(v);
    return (ushort)((u + 0x7FFFu + ((u >> 16) & 1u)) >> 16);
}
__device__ __forceinline__ float bf16_to_f(ushort h) {
    return __uint_as_float(((unsigned)h) << 16);
}

// ---------------------------------------------------------------------------
// W-only conversion (tiny): W fp32 [k][n] -> hi/lo bf16 TRANSPOSED [n][k].
// ---------------------------------------------------------------------------
__global__ __launch_bounds__(256) void wconv(
    const float* __restrict__ wq, const float* __restrict__ wk,
    ushort* __restrict__ wqh, ushort* __restrict__ wql,
    ushort* __restrict__ wkh, ushort* __restrict__ wkl)
{
    int widx = blockIdx.x * 256 + threadIdx.x;     // 0..32767
    const float* W; ushort *wh, *wl;
    if (widx < 16384) { W = wq; wh = wqh; wl = wql; }
    else { W = wk; wh = wkh; wl = wkl; widx -= 16384; }
    int n  = widx >> 6;
    int k4 = (widx & 63) * 4;
    ushort hh[4], ll[4];
    #pragma unroll
    for (int c = 0; c < 4; ++c) {
        float v = W[(k4 + c) * 256 + n];
        hh[c] = bf16_rne(v);
        ll[c] = bf16_rne(v - bf16_to_f(hh[c]));
    }
    *(ushort4*)&wh[n * 256 + k4] = make_ushort4(hh[0], hh[1], hh[2], hh[3]);
    *(ushort4*)&wl[n * 256 + k4] = make_ushort4(ll[0], ll[1], ll[2], ll[3]);
}

// ---------------------------------------------------------------------------
// Projection GEMM with FUSED A-conversion (unchanged).
// epilogue: exp2(acc*scale) so score kernel consumes EQ=e^{2q}, EK=e^{2k}.
// ---------------------------------------------------------------------------
__global__ __launch_bounds__(256, 2) void proj_fused(
    const float* __restrict__ queries, const float* __restrict__ keys,
    const ushort* __restrict__ wqh, const ushort* __restrict__ wql,
    const ushort* __restrict__ wkh, const ushort* __restrict__ wkl,
    float* __restrict__ qp, float* __restrict__ kp, float scale)
{
    __shared__ ushort AsH[64 * 64], AsL[64 * 64];
    __shared__ ushort BsH[64 * 64], BsL[64 * 64];

    const float* A; const ushort *Bh, *Bl; float* C; int rows0;
    const int bx = blockIdx.x;
    if (bx < 16) { A = queries; Bh = wqh; Bl = wql; C = qp; rows0 = bx * 64; }
    else         { A = keys;    Bh = wkh; Bl = wkl; C = kp; rows0 = (bx - 16) * 64; }
    const int cols0 = blockIdx.y * 64;

    const int t = threadIdx.x, lane = t & 63, wave = t >> 6;
    const int quad = lane >> 4, l15 = lane & 15;
    const int sr  = t >> 2;
    const int sc2 = (t & 3) * 2;

    f32x4 acc[4];
    #pragma unroll
    for (int j = 0; j < 4; ++j) acc[j] = (f32x4){0.f, 0.f, 0.f, 0.f};

    for (int k0 = 0; k0 < 256; k0 += 64) {
        const float* arow = &A[(size_t)(rows0 + sr) * 256 + k0 + sc2 * 8];
        float4 a0 = *(const float4*)&arow[0];
        float4 a1 = *(const float4*)&arow[4];
        float4 a2 = *(const float4*)&arow[8];
        float4 a3 = *(const float4*)&arow[12];
        const ushort* bhp = &Bh[(size_t)(cols0 + sr) * 256 + k0 + sc2 * 8];
        const ushort* blp = &Bl[(size_t)(cols0 + sr) * 256 + k0 + sc2 * 8];
        short8 b0h = *(const short8*)&bhp[0];
        short8 b1h = *(const short8*)&bhp[8];
        short8 b0l = *(const short8*)&blp[0];
        short8 b1l = *(const short8*)&blp[8];

        __syncthreads();

        float av[16] = {a0.x, a0.y, a0.z, a0.w, a1.x, a1.y, a1.z, a1.w,
                        a2.x, a2.y, a2.z, a2.w, a3.x, a3.y, a3.z, a3.w};
        short8 ah0, ah1, al0, al1;
        #pragma unroll
        for (int e = 0; e < 8; ++e) {
            ushort h0 = bf16_rne(av[e]);
            ushort h1 = bf16_rne(av[8 + e]);
            ah0[e] = (short)h0;
            ah1[e] = (short)h1;
            al0[e] = (short)bf16_rne(av[e] - bf16_to_f(h0));
            al1[e] = (short)bf16_rne(av[8 + e] - bf16_to_f(h1));
        }
        {
            int s0 = sr * 8 + ((sc2 + 0) ^ (sr & 7));
            int s1 = sr * 8 + ((sc2 + 1) ^ (sr & 7));
            *(short8*)&AsH[s0 * 8] = ah0;
            *(short8*)&AsH[s1 * 8] = ah1;
            *(short8*)&AsL[s0 * 8] = al0;
            *(short8*)&AsL[s1 * 8] = al1;
            *(short8*)&BsH[s0 * 8] = b0h;
            *(short8*)&BsH[s1 * 8] = b1h;
            *(short8*)&BsL[s0 * 8] = b0l;
            *(short8*)&BsL[s1 * 8] = b1l;
        }
        __syncthreads();

        #pragma unroll
        for (int ks = 0; ks < 2; ++ks) {
            const int c = ks * 4 + quad;
            short8 aH, aL, bH[4], bL[4];
            {
                int r = wave * 16 + l15;
                int slot = r * 8 + (c ^ (r & 7));
                aH = *(const short8*)&AsH[slot * 8];
                aL = *(const short8*)&AsL[slot * 8];
            }
            #pragma unroll
            for (int ns = 0; ns < 4; ++ns) {
                int n = ns * 16 + l15;
                int slot = n * 8 + (c ^ (n & 7));
                bH[ns] = *(const short8*)&BsH[slot * 8];
                bL[ns] = *(const short8*)&BsL[slot * 8];
            }
            #pragma unroll
            for (int ns = 0; ns < 4; ++ns)
                acc[ns] = __builtin_amdgcn_mfma_f32_16x16x32_bf16(aH, bH[ns], acc[ns], 0, 0, 0);
            #pragma unroll
            for (int ns = 0; ns < 4; ++ns)
                acc[ns] = __builtin_amdgcn_mfma_f32_16x16x32_bf16(aL, bH[ns], acc[ns], 0, 0, 0);
            #pragma unroll
            for (int ns = 0; ns < 4; ++ns)
                acc[ns] = __builtin_amdgcn_mfma_f32_16x16x32_bf16(aH, bL[ns], acc[ns], 0, 0, 0);
        }
    }

    const int rbase = rows0 + wave * 16 + quad * 4;
    #pragma unroll
    for (int ns = 0; ns < 4; ++ns) {
        int col = cols0 + ns * 16 + l15;
        #pragma unroll
        for (int r = 0; r < 4; ++r)
            C[(size_t)(rbase + r) * 256 + col] =
                __builtin_amdgcn_exp2f(acc[ns][r] * scale);
    }
}

// ---------------------------------------------------------------------------
// score_a: PURE score kernel.  Block = (b, qt8, seg64), 1024 blocks, 256 thr.
// Writes Pt[b][k][64q] = e^{score} (no-max softmax numerator; masked -> 0)
// and NOTHING else: no Ps exchange, no PV, no cross-wave reduce, ONE barrier.
// LDS 9.3 KB, VGPR ~105 -> ~16 waves/CU, all blocks resident; dead blocks
// retire instantly.  The monolith's ~40us was phase-serialization; this
// kernel is the score phase alone at high occupancy.
// ---------------------------------------------------------------------------
__global__ __launch_bounds__(256, 4) void score_a(
    const float* __restrict__ qp,      // [B*NQ, H]  EQ = exp2(q * 2/ln2)
    const float* __restrict__ kp,      // [B*NK, H]  EK = exp2(k * 2/ln2)
    const int*   __restrict__ vlens,   // [B]
    const float* __restrict__ w_v,     // [H]
    float* __restrict__ Pt)            // [B][NK][64]  P^T
{
    __shared__ float eq[8][260];
    __shared__ float wv[HD];

    const int b   = blockIdx.x & 15;
    const int qt  = blockIdx.x >> 4;    // 0..7
    const int seg = blockIdx.y;         // 0..7
    const int vl  = vlens[b];
    if (seg * 64 >= vl) return;

    const int t = threadIdx.x, lane = t & 63, wave = t >> 6;
    const int key = wave * 16 + (lane >> 2);   // 0..63
    const int ch  = lane & 3;
    const int kg  = seg * 64 + key;

    // prefetch full ek row (16 float4); drains at the one barrier below,
    // overlapped with the eq/wv staging loads.
    const float* krow = kp + ((size_t)b * NK + kg) * HD + ch * 4;
    float4 ek[16];
    #pragma unroll
    for (int j = 0; j < 16; ++j) ek[j] = *(const float4*)&krow[j * 16];

    const float* qsrc = qp + ((size_t)b * NQ + qt * 8) * HD;
    #pragma unroll
    for (int i = 0; i < 2; ++i) {
        int idx = i * 256 + t;
        int row = idx >> 6, c4 = (idx & 63) * 4;
        *(float4*)&eq[row][c4] = *(const float4*)&qsrc[(size_t)row * HD + c4];
    }
    if (t < 64) *(float4*)&wv[t * 4] = *(const float4*)&w_v[t * 4];
    __syncthreads();

    float Wsum;
    {
        float ws = wv[lane] + wv[lane + 64] + wv[lane + 128] + wv[lane + 192];
        #pragma unroll
        for (int off = 32; off; off >>= 1) ws += __shfl_xor(ws, off);
        Wsum = ws;
    }

    // scores: 4-way grouped reciprocal, ek from regs, eq/wv LDS broadcast
    float s[8] = {0.f, 0.f, 0.f, 0.f, 0.f, 0.f, 0.f, 0.f};
    #pragma unroll
    for (int j = 0; j < 16; ++j) {
        const int h = j * 16 + ch * 4;
        float4 e4 = ek[j];
        float4 w4 = *(const float4*)&wv[h];
        #pragma unroll
        for (int qi = 0; qi < 8; ++qi) {
            float4 q4 = *(const float4*)&eq[qi][h];
            float p0 = fmaf(q4.x, e4.x, 1.f);
            float p1 = fmaf(q4.y, e4.y, 1.f);
            float p2 = fmaf(q4.z, e4.z, 1.f);
            float p3 = fmaf(q4.w, e4.w, 1.f);
            float d01 = p0 * p1;
            float d23 = p2 * p3;
            float n01 = fmaf(w4.x, p1, w4.y * p0);
            float n23 = fmaf(w4.z, p3, w4.w * p2);
            float num = fmaf(d01, n23, d23 * n01);
            float r   = __builtin_amdgcn_rcpf(d01 * d23);
            s[qi] = fmaf(num, r, s[qi]);
        }
    }
    #pragma unroll
    for (int qi = 0; qi < 8; ++qi) {
        s[qi] += __shfl_xor(s[qi], 1);
        s[qi] += __shfl_xor(s[qi], 2);
    }

    if (ch == 0) {
        const bool masked = (kg >= vl);
        const float L2E = 1.4426950408889634f;
        float pt[8];
        #pragma unroll
        for (int qi = 0; qi < 8; ++qi) {
            float sv = fmaf(-2.f, s[qi], Wsum);      // |score| <= ~13
            pt[qi] = masked ? 0.f : __builtin_amdgcn_exp2f(sv * L2E);
        }
        float* dst = &Pt[((size_t)b * NK + kg) * 64 + qt * 8];
        *(float4*)&dst[0] = make_float4(pt[0], pt[1], pt[2], pt[3]);
        *(float4*)&dst[4] = make_float4(pt[4], pt[5], pt[6], pt[7]);
    }
}

// ---------------------------------------------------------------------------
// pv_b: O = P.V streaming GEMM fused with L = sum_k p and the division.
// Grid 512 = (b | qt8 | vd64-quarter); b in low bits so same-b blocks share
// an XCD L2 (V[b] = 4 MB reuse).  Thread = (vd4 0..15, q 0..7, k-parity);
// k-loop has fully independent loads (unroll 8), one LDS pair-reduce.
// Replaces the monolith's PV + the combine kernel + pO/pL traffic.
// ---------------------------------------------------------------------------
__global__ __launch_bounds__(256) void pv_b(
    const float* __restrict__ Pt,      // [B][NK][64]
    const float* __restrict__ values,  // [B][NK][256]
    const int*   __restrict__ vlens,
    float* __restrict__ out)           // [B*NQ, 256]
{
    __shared__ f32x4 red[128];
    __shared__ float Lred[8];
    __shared__ float Lfin[8];

    const int bx  = blockIdx.x;
    const int b   = bx & 15;
    const int qt  = (bx >> 4) & 7;
    const int vdq = bx >> 7;            // 0..3
    const int vl  = vlens[b];
    const int nk  = ((vl + 63) >> 6) << 6;   // alive keys, seg-rounded

    const int t   = threadIdx.x;
    const int vd4 = t & 15;
    const int q   = (t >> 4) & 7;
    const int kp2 = t >> 7;             // 0..1

    const float* vptr = values + (size_t)b * NK * HD + vdq * 64 + vd4 * 4;
    const float* pptr = Pt + (size_t)b * NK * 64 + qt * 8 + q;

    f32x4 acc = (f32x4){0.f, 0.f, 0.f, 0.f};
    float Lacc = 0.f;
    #pragma unroll 8
    for (int k = kp2; k < nk; k += 2) {
        float  p = pptr[(size_t)k * 64];          // broadcast across vd4
        float4 v = *(const float4*)&vptr[(size_t)k * HD];
        acc[0] = fmaf(p, v.x, acc[0]);
        acc[1] = fmaf(p, v.y, acc[1]);
        acc[2] = fmaf(p, v.z, acc[2]);
        acc[3] = fmaf(p, v.w, acc[3]);
        Lacc += p;
    }

    if (kp2 == 1) {
        red[t - 128] = acc;
        if (vd4 == 0) Lred[q] = Lacc;
    }
    __syncthreads();
    if (kp2 == 0) {
        f32x4 o = red[t];
        acc[0] += o[0]; acc[1] += o[1]; acc[2] += o[2]; acc[3] += o[3];
        if (vd4 == 0) Lfin[q] = Lacc + Lred[q];
    }
    __syncthreads();
    if (kp2 == 0) {
        float r = __builtin_amdgcn_rcpf(Lfin[q]);
        float4 o = make_float4(acc[0] * r, acc[1] * r, acc[2] * r, acc[3] * r);
        *(float4*)&out[((size_t)(b * 64 + qt * 8 + q)) * 256 + vdq * 64 + vd4 * 4] = o;
    }
}

extern "C" void kernel_launch(void* const* d_in, const int* in_sizes, int n_in,
                              void* d_out, int out_size, void* d_ws, size_t ws_size,
                              hipStream_t stream) {
    const float* queries = (const float*)d_in[0];
    const float* keys    = (const float*)d_in[1];
    const float* values  = (const float*)d_in[2];
    const int*   vlens   = (const int*)d_in[3];
    const float* W_q     = (const float*)d_in[4];
    const float* W_k     = (const float*)d_in[5];
    const float* w_v     = (const float*)d_in[6];
    float* out = (float*)d_out;

    // ws layout (~11.5 MB of 256 MiB):
    float*  kp  = (float*)d_ws;                          // 8 MB
    float*  qp  = kp + (size_t)BB * NK * HD;             // 1 MB
    float*  Pt  = qp + (size_t)BB * NQ * HD;             // 2 MB  [B][NK][64]
    ushort* wqh = (ushort*)(Pt + (size_t)BB * NK * 64);
    ushort* wql = wqh + 65536;
    ushort* wkh = wql + 65536;
    ushort* wkl = wkh + 65536;

    const float SC = 2.885390081777927f;                 // 2/ln(2)

    wconv<<<dim3(128), 256, 0, stream>>>(W_q, W_k, wqh, wql, wkh, wkl);
    proj_fused<<<dim3(144, 4), 256, 0, stream>>>(queries, keys,
                                                 wqh, wql, wkh, wkl,
                                                 qp, kp, SC);
    score_a<<<dim3(128, 8), 256, 0, stream>>>(qp, kp, vlens, w_v, Pt);
    pv_b<<<dim3(512), 256, 0, stream>>>(Pt, values, vlens, out);
}